// Round 2
// baseline (1817.560 us; speedup 1.0000x reference)
//
#include <hip/hip_runtime.h>
#include <math.h>

// Swin window attention, fully fused, fp32 baseline.
// One 256-thread workgroup per window (B_=4096 windows).
// Phases: load x -> QKV GEMM -> per-head (QK^T+bias+mask -> softmax -> PV) -> proj GEMM.

#define NTOK   49      // tokens per window (7x7)
#define CDIM   128     // channels
#define NHEAD  4
#define HDIM   32
#define C3     384     // 3*CDIM
#define NWIN   256     // mask windows
#define QKV_LD 129     // padded LDS stride (odd -> conflict-free K^T reads)
#define BLOCK  256

__global__ __launch_bounds__(BLOCK, 1)
void win_attn_fused(const float* __restrict__ x,
                    const float* __restrict__ mask,
                    const float* __restrict__ qkv_w,
                    const float* __restrict__ qkv_b,
                    const float* __restrict__ proj_w,
                    const float* __restrict__ proj_b,
                    const float* __restrict__ bias_table,
                    float* __restrict__ out) {
    // xa doubles as the attention-output (ao) buffer after QKV phase consumes x.
    __shared__ float xa[NTOK * CDIM];        // 25,088 B
    __shared__ float qs[NTOK * QKV_LD];      // 25,284 B (q, pre-scaled)
    __shared__ float ks_[NTOK * QKV_LD];     // 25,284 B
    __shared__ float vs[NTOK * QKV_LD];      // 25,284 B
    __shared__ float S[NTOK * NTOK];         //  9,604 B   total ~108 KB

    const int b   = blockIdx.x;
    const int tid = threadIdx.x;
    const float scale = 0.17677669529663687f;  // 1/sqrt(32)

    // ---- Phase 0: stage x tile (49x128 = 1568 float4), coalesced ----
    {
        const float4* src = (const float4*)(x + (size_t)b * (NTOK * CDIM));
        float4* dst = (float4*)xa;
        for (int i = tid; i < NTOK * CDIM / 4; i += BLOCK) dst[i] = src[i];
    }
    __syncthreads();

    // ---- Phase 1: qkv = x @ qkv_w + qkv_b -> q(scaled)/k/v in LDS ----
    // Tasks: 7 row-groups x 384 cols = 2688; each task computes 7 rows (reg tile).
    // One global w-load amortized over 7 FMAs; x reads are LDS broadcasts.
    for (int task = tid; task < 7 * C3; task += BLOCK) {
        const int rg = task / C3;   // 0..6
        const int c  = task % C3;   // 0..383
        float acc[7];
        const float bia = qkv_b[c];
        #pragma unroll
        for (int j = 0; j < 7; ++j) acc[j] = bia;
        const float* wcol = qkv_w + c;
        #pragma unroll 4
        for (int k = 0; k < CDIM; ++k) {
            const float wv = wcol[(size_t)k * C3];
            #pragma unroll
            for (int j = 0; j < 7; ++j)
                acc[j] += xa[(rg * 7 + j) * CDIM + k] * wv;
        }
        #pragma unroll
        for (int j = 0; j < 7; ++j) {
            const int n = rg * 7 + j;
            if (c < CDIM)            qs [n * QKV_LD + c]            = acc[j] * scale;
            else if (c < 2 * CDIM)   ks_[n * QKV_LD + (c - CDIM)]   = acc[j];
            else                     vs [n * QKV_LD + (c - 2*CDIM)] = acc[j];
        }
    }

    // ---- Phase 2: per-head attention ----
    const float* mwin = mask + (size_t)(b % NWIN) * (NTOK * NTOK);
    for (int h = 0; h < NHEAD; ++h) {
        __syncthreads();   // qkv ready (h=0) / prev PV done reading S (h>0)

        // S = (q*scale) @ k^T + rel_pos_bias + mask    (2401 entries, dot-32)
        for (int t = tid; t < NTOK * NTOK; t += BLOCK) {
            const int n = t / NTOK, m = t % NTOK;
            const float* qrow = qs  + n * QKV_LD + h * HDIM;
            const float* krow = ks_ + m * QKV_LD + h * HDIM;
            float acc = 0.f;
            #pragma unroll
            for (int d = 0; d < HDIM; ++d) acc += qrow[d] * krow[d];
            const int i0 = n / 7, i1 = n % 7, j0 = m / 7, j1 = m % 7;
            const int ridx = (i0 - j0 + 6) * 13 + (i1 - j1 + 6);
            acc += bias_table[ridx * NHEAD + h];
            acc += mwin[t];
            S[t] = acc;
        }
        __syncthreads();

        // softmax per row (49 rows, one thread each; cheap)
        if (tid < NTOK) {
            float* row = S + tid * NTOK;
            float mx = row[0];
            for (int m = 1; m < NTOK; ++m) mx = fmaxf(mx, row[m]);
            float sum = 0.f;
            for (int m = 0; m < NTOK; ++m) { const float e = expf(row[m] - mx); sum += e; row[m] = e; }
            const float inv = 1.f / sum;
            for (int m = 0; m < NTOK; ++m) row[m] *= inv;
        }
        __syncthreads();

        // PV: ao[n][h*32+d] = S @ v_h   (1568 entries, dot-49)
        for (int t = tid; t < NTOK * HDIM; t += BLOCK) {
            const int n = t / HDIM, d = t % HDIM;
            const float* srow = S + n * NTOK;
            const float* vcol = vs + h * HDIM + d;
            float acc = 0.f;
            #pragma unroll
            for (int m = 0; m < NTOK; ++m) acc += srow[m] * vcol[m * QKV_LD];
            xa[n * CDIM + h * HDIM + d] = acc;   // xa now = attention output
        }
    }
    __syncthreads();

    // ---- Phase 3: out = ao @ proj_w + proj_b ----
    // Tasks: 7 row-groups x 128 cols = 896; 7-row register tile like phase 1.
    float* orow = out + (size_t)b * (NTOK * CDIM);
    for (int task = tid; task < 7 * CDIM; task += BLOCK) {
        const int rg = task / CDIM;
        const int c  = task % CDIM;
        float acc[7];
        const float pb = proj_b[c];
        #pragma unroll
        for (int j = 0; j < 7; ++j) acc[j] = pb;
        const float* wcol = proj_w + c;
        #pragma unroll 4
        for (int k = 0; k < CDIM; ++k) {
            const float wv = wcol[(size_t)k * CDIM];
            #pragma unroll
            for (int j = 0; j < 7; ++j)
                acc[j] += xa[(rg * 7 + j) * CDIM + k] * wv;
        }
        #pragma unroll
        for (int j = 0; j < 7; ++j)
            orow[(rg * 7 + j) * CDIM + c] = acc[j];
    }
}

extern "C" void kernel_launch(void* const* d_in, const int* in_sizes, int n_in,
                              void* d_out, int out_size, void* d_ws, size_t ws_size,
                              hipStream_t stream) {
    const float* x          = (const float*)d_in[0];
    const float* mask       = (const float*)d_in[1];
    const float* qkv_w      = (const float*)d_in[2];
    const float* qkv_b      = (const float*)d_in[3];
    const float* proj_w     = (const float*)d_in[4];
    const float* proj_b     = (const float*)d_in[5];
    const float* bias_table = (const float*)d_in[6];
    float* out = (float*)d_out;

    hipLaunchKernelGGL(win_attn_fused, dim3(4096), dim3(BLOCK), 0, stream,
                       x, mask, qkv_w, qkv_b, proj_w, proj_b, bias_table, out);
}

// Round 3
// 172.345 us; speedup vs baseline: 10.5461x; 10.5461x over previous
//
#include <hip/hip_runtime.h>

// Swin window attention, fully fused, bf16-MFMA version.
// Kernel 1 (prep_w): pre-swizzle qkv_w/proj_w into MFMA B-fragment order (bf16) in d_ws.
// Kernel 2 (win_attn): one 4-wave block per window; M padded 49->64.
//   LDS: qk[64][264] (q,k; q region reused as attn-out), xs[64][136] (x, then P),
//        vt[128][72] (V transposed at QKV-store time). Total 69.6 KB -> 2 blocks/CU.
// MFMA 16x16x32 bf16 layouts (m89/m91-verified):
//   src0 A: lane holds A[lane&15][(lane>>4)*8+j]
//   src1 B: lane holds B[(lane>>4)*8+j][lane&15]
//   D:      lane holds D[(lane>>4)*4+r][lane&15]

typedef __attribute__((ext_vector_type(8))) short bf16x8;
typedef __attribute__((ext_vector_type(4))) short short4v;
typedef __attribute__((ext_vector_type(4))) float f32x4;

#define NTOK  49
#define CDIM  128
#define NWIN  256
#define LDQK  264     // bf16 stride: 528 B = 33*16, row-step 132 dw == 4 mod 32
#define LDX   136     // 272 B = 17*16
#define LDVT  72      // 144 B = 9*16
#define SCALE 0.17677669529663687f
#define PROJ_WOFF 49152   // shorts: 96 frags * 512

static __device__ __forceinline__ short f2bf(float f) {
    union { float f; unsigned u; } v; v.f = f;
    unsigned r = v.u + 0x7FFFu + ((v.u >> 16) & 1u);   // RNE
    return (short)(r >> 16);
}

// ---- weight pre-swizzle: frag(nt,kt), lane l -> 8 consecutive bf16 (16B) ----
__global__ void prep_w(const float* __restrict__ qkv_w,
                       const float* __restrict__ proj_w,
                       short* __restrict__ wb) {
    const int fid = blockIdx.x;     // 0..127 (96 qkv + 32 proj)
    const int l   = threadIdx.x;    // 0..63
    const int lq = l & 15, lg = l >> 4;
    bf16x8 v;
    if (fid < 96) {
        const int nt = fid >> 2, kk = fid & 3;
        #pragma unroll
        for (int j = 0; j < 8; ++j)
            v[j] = f2bf(qkv_w[(kk*32 + lg*8 + j)*384 + nt*16 + lq]);
        *(bf16x8*)(wb + fid*512 + l*8) = v;
    } else {
        const int f2 = fid - 96;
        const int nt = f2 >> 2, kk = f2 & 3;
        #pragma unroll
        for (int j = 0; j < 8; ++j)
            v[j] = f2bf(proj_w[(kk*32 + lg*8 + j)*128 + nt*16 + lq]);
        *(bf16x8*)(wb + PROJ_WOFF + f2*512 + l*8) = v;
    }
}

__global__ __launch_bounds__(256, 2)
void win_attn(const float* __restrict__ x,
              const float* __restrict__ mask,
              const float* __restrict__ qkv_b,
              const float* __restrict__ proj_b,
              const float* __restrict__ bias_table,
              const short* __restrict__ wb,
              float* __restrict__ out) {
    __shared__ __align__(16) short qk[64 * LDQK];   // 33792 B
    __shared__ __align__(16) short xs[64 * LDX];    // 17408 B
    __shared__ __align__(16) short vt[128 * LDVT];  // 18432 B

    const int b    = blockIdx.x;
    const int tid  = threadIdx.x;
    const int l    = tid & 63;
    const int wave = tid >> 6;
    const int lq   = l & 15, lg = l >> 4;

    // ---- Phase 0: zero x pad rows; stage x -> bf16 LDS ----
    {
        int* xz = (int*)(xs + NTOK * LDX);          // 6664 shorts -> int-aligned
        for (int i = tid; i < (64 - NTOK) * LDX / 2; i += 256) xz[i] = 0;
        const float4* src = (const float4*)(x + (size_t)b * (NTOK * CDIM));
        for (int i = tid; i < NTOK * CDIM / 4; i += 256) {
            float4 f = src[i];
            const int fo = i * 4, r = fo >> 7, c = fo & 127;
            short4v s; s[0] = f2bf(f.x); s[1] = f2bf(f.y); s[2] = f2bf(f.z); s[3] = f2bf(f.w);
            *(short4v*)(xs + r * LDX + c) = s;
        }
    }
    __syncthreads();

    // ---- Phase 1: QKV GEMM. Waves split N (6 tiles each of 24). A resident in regs. ----
    bf16x8 af[4][4];
    #pragma unroll
    for (int m = 0; m < 4; ++m)
        #pragma unroll
        for (int kk = 0; kk < 4; ++kk)
            af[m][kk] = *(const bf16x8*)(xs + (m*16 + lq)*LDX + kk*32 + lg*8);

    for (int t = 0; t < 6; ++t) {
        const int nt = wave * 6 + t;                 // 0..23 (q:0-7, k:8-15, v:16-23)
        bf16x8 bf_[4];
        #pragma unroll
        for (int kk = 0; kk < 4; ++kk)
            bf_[kk] = *(const bf16x8*)(wb + (nt*4 + kk)*512 + l*8);
        const float bia = qkv_b[nt*16 + lq];
        f32x4 acc[4];
        #pragma unroll
        for (int m = 0; m < 4; ++m) acc[m] = (f32x4){bia, bia, bia, bia};
        #pragma unroll
        for (int kk = 0; kk < 4; ++kk)
            #pragma unroll
            for (int m = 0; m < 4; ++m)
                acc[m] = __builtin_amdgcn_mfma_f32_16x16x32_bf16(af[m][kk], bf_[kk], acc[m], 0, 0, 0);
        if (nt < 16) {                               // q (scaled) and k -> qk[tok][col]
            const float sc = (nt < 8) ? SCALE : 1.0f;
            #pragma unroll
            for (int m = 0; m < 4; ++m)
                #pragma unroll
                for (int r = 0; r < 4; ++r)
                    qk[(m*16 + lg*4 + r)*LDQK + nt*16 + lq] = f2bf(acc[m][r] * sc);
        } else {                                     // v -> transposed vt[dim][tok]
            #pragma unroll
            for (int m = 0; m < 4; ++m)
                #pragma unroll
                for (int r = 0; r < 4; ++r)
                    vt[((nt - 16)*16 + lq)*LDVT + m*16 + lg*4 + r] = f2bf(acc[m][r]);
        }
    }
    __syncthreads();

    // ---- Phase 2: attention. Wave owns q-row stripe m0..m0+15. ----
    const float* mwin = mask + (size_t)(b & (NWIN - 1)) * (NTOK * NTOK);
    const int m0 = wave * 16;

    // hoisted bias-gather indices / mask values / validity (head-independent)
    int   ridx_[4][4];
    float mval_[4][4];
    #pragma unroll
    for (int nt = 0; nt < 4; ++nt) {
        const int kt = nt*16 + lq;
        #pragma unroll
        for (int r = 0; r < 4; ++r) {
            const int q = m0 + lg*4 + r;
            if (q < NTOK && kt < NTOK) {
                ridx_[nt][r] = ((q/7 - kt/7 + 6)*13 + (q%7 - kt%7 + 6)) * 4;
                mval_[nt][r] = mwin[q*NTOK + kt];
            } else {
                ridx_[nt][r] = -1;
                mval_[nt][r] = 0.f;
            }
        }
    }

    for (int h = 0; h < 4; ++h) {
        // S = (q*scale) @ k^T   (K=32 exactly one MFMA step)
        bf16x8 aq = *(const bf16x8*)(qk + (m0 + lq)*LDQK + h*32 + lg*8);
        f32x4 s[4];
        #pragma unroll
        for (int nt = 0; nt < 4; ++nt) {
            bf16x8 bk = *(const bf16x8*)(qk + (nt*16 + lq)*LDQK + 128 + h*32 + lg*8);
            f32x4 z = {0.f, 0.f, 0.f, 0.f};
            s[nt] = __builtin_amdgcn_mfma_f32_16x16x32_bf16(aq, bk, z, 0, 0, 0);
        }
        // + rel-pos bias + mask; pad -> -1e30
        #pragma unroll
        for (int nt = 0; nt < 4; ++nt)
            #pragma unroll
            for (int r = 0; r < 4; ++r) {
                if (ridx_[nt][r] >= 0)
                    s[nt][r] += bias_table[ridx_[nt][r] + h] + mval_[nt][r];
                else
                    s[nt][r] = -1e30f;
            }
        // in-register softmax over 64 cols (4 frags x 16 lanes)
        float mx[4], sum[4], inv[4];
        #pragma unroll
        for (int r = 0; r < 4; ++r)
            mx[r] = fmaxf(fmaxf(s[0][r], s[1][r]), fmaxf(s[2][r], s[3][r]));
        #pragma unroll
        for (int w = 1; w <= 8; w <<= 1)
            #pragma unroll
            for (int r = 0; r < 4; ++r)
                mx[r] = fmaxf(mx[r], __shfl_xor(mx[r], w, 64));
        #pragma unroll
        for (int r = 0; r < 4; ++r) sum[r] = 0.f;
        #pragma unroll
        for (int nt = 0; nt < 4; ++nt)
            #pragma unroll
            for (int r = 0; r < 4; ++r) {
                const float p = __expf(s[nt][r] - mx[r]);
                s[nt][r] = p; sum[r] += p;
            }
        #pragma unroll
        for (int w = 1; w <= 8; w <<= 1)
            #pragma unroll
            for (int r = 0; r < 4; ++r)
                sum[r] += __shfl_xor(sum[r], w, 64);
        #pragma unroll
        for (int r = 0; r < 4; ++r) inv[r] = 1.0f / sum[r];
        // P -> bf16 in xs (own stripe rows only)
        #pragma unroll
        for (int nt = 0; nt < 4; ++nt)
            #pragma unroll
            for (int r = 0; r < 4; ++r)
                xs[(m0 + lg*4 + r)*LDX + nt*16 + lq] = f2bf(s[nt][r] * inv[r]);

        __syncthreads();   // all waves' q[h]/k[h] reads done before ao overwrites q[h]

        // PV: out_h = P @ V_h  (K=64 -> 2 steps; V from transposed vt, contiguous reads)
        bf16x8 pa[2];
        #pragma unroll
        for (int kk = 0; kk < 2; ++kk)
            pa[kk] = *(const bf16x8*)(xs + (m0 + lq)*LDX + kk*32 + lg*8);
        #pragma unroll
        for (int dn = 0; dn < 2; ++dn) {
            f32x4 o = {0.f, 0.f, 0.f, 0.f};
            #pragma unroll
            for (int kk = 0; kk < 2; ++kk) {
                bf16x8 bv = *(const bf16x8*)(vt + (h*32 + dn*16 + lq)*LDVT + kk*32 + lg*8);
                o = __builtin_amdgcn_mfma_f32_16x16x32_bf16(pa[kk], bv, o, 0, 0, 0);
            }
            #pragma unroll
            for (int r = 0; r < 4; ++r)   // attn-out over q region (cols h*32..h*32+31)
                qk[(m0 + lg*4 + r)*LDQK + h*32 + dn*16 + lq] = f2bf(o[r]);
        }
    }
    __syncthreads();   // ao complete (proj reads all waves' stripes)

    // ---- Phase 3: proj GEMM. Waves split N (2 tiles each of 8). ----
    bf16x8 pa2[4][4];
    #pragma unroll
    for (int m = 0; m < 4; ++m)
        #pragma unroll
        for (int kk = 0; kk < 4; ++kk)
            pa2[m][kk] = *(const bf16x8*)(qk + (m*16 + lq)*LDQK + kk*32 + lg*8);

    float* ob = out + (size_t)b * (NTOK * CDIM);
    for (int t = 0; t < 2; ++t) {
        const int nt = wave * 2 + t;                 // 0..7
        bf16x8 bw[4];
        #pragma unroll
        for (int kk = 0; kk < 4; ++kk)
            bw[kk] = *(const bf16x8*)(wb + PROJ_WOFF + (nt*4 + kk)*512 + l*8);
        const float pb = proj_b[nt*16 + lq];
        f32x4 oc[4];
        #pragma unroll
        for (int m = 0; m < 4; ++m) oc[m] = (f32x4){pb, pb, pb, pb};
        #pragma unroll
        for (int kk = 0; kk < 4; ++kk)
            #pragma unroll
            for (int m = 0; m < 4; ++m)
                oc[m] = __builtin_amdgcn_mfma_f32_16x16x32_bf16(pa2[m][kk], bw[kk], oc[m], 0, 0, 0);
        #pragma unroll
        for (int m = 0; m < 4; ++m)
            #pragma unroll
            for (int r = 0; r < 4; ++r) {
                const int row = m*16 + lg*4 + r;
                if (row < NTOK) ob[row*CDIM + nt*16 + lq] = oc[m][r];
            }
    }
}

extern "C" void kernel_launch(void* const* d_in, const int* in_sizes, int n_in,
                              void* d_out, int out_size, void* d_ws, size_t ws_size,
                              hipStream_t stream) {
    (void)in_sizes; (void)n_in; (void)out_size; (void)ws_size;
    const float* x          = (const float*)d_in[0];
    const float* mask       = (const float*)d_in[1];
    const float* qkv_w      = (const float*)d_in[2];
    const float* qkv_b      = (const float*)d_in[3];
    const float* proj_w     = (const float*)d_in[4];
    const float* proj_b     = (const float*)d_in[5];
    const float* bias_table = (const float*)d_in[6];
    float* out = (float*)d_out;
    short* wb  = (short*)d_ws;   // 131072 B used

    hipLaunchKernelGGL(prep_w,   dim3(128),  dim3(64),  0, stream, qkv_w, proj_w, wb);
    hipLaunchKernelGGL(win_attn, dim3(4096), dim3(256), 0, stream,
                       x, mask, qkv_b, proj_b, bias_table, wb, out);
}

// Round 5
// 154.835 us; speedup vs baseline: 11.7387x; 1.1131x over previous
//
#include <hip/hip_runtime.h>
#include <hip/hip_bf16.h>

// Swin window attention, fully fused, bf16-MFMA, transposed-operand version.
// All GEMMs computed transposed (D = B^T·A^T) so D-fragments have consecutive
// registers = consecutive addresses -> vectorized stores everywhere.
//   phase1: QKV^T = Wqkv^T · x^T   (x B-frags straight from global, no LDS stage)
//   phase2: S^T = K · Q^T  -> in-lane softmax -> P repack (shfl) -> ao^T = V^T·P^T
//   phase3: out^T = Wp^T · ao^T -> coalesced dwordx4 global stores
// LDS: qa[64][136] (q, overlaid by ao), kl[64][136], vt[128][72] = 52 KB -> 3 blocks/CU.
// MFMA 16x16x32 bf16 layouts (validated end-to-end by the round-3 pass):
//   src0 A: lane holds A[lane&15][(lane>>4)*8+j]
//   src1 B: lane holds B[(lane>>4)*8+j][lane&15]
//   D:      lane holds D[(lane>>4)*4+r][lane&15]
// NOTE: round-4 used inline-asm v_cvt_pk_bf16_f32 and produced NaN; this round
// uses only hip_bf16.h intrinsics (compiler emits cvt_pk itself, per m240).

typedef __attribute__((ext_vector_type(8))) short bf16x8;
typedef __attribute__((ext_vector_type(4))) float f32x4;

#define NTOK  49
#define CDIM  128
#define NWIN  256
#define LDQ   136     // shorts; 272 B row stride = 16B*17 (odd 16B multiplier -> 2-way free b128/b64)
#define LDV   72      // shorts; 144 B row stride
#define SCALE 0.17677669529663687f
#define PROJ_WOFF 49152   // shorts: 96 frags * 512

static __device__ __forceinline__ unsigned pk2(float a, float b) {
    __hip_bfloat162 h = __float22bfloat162_rn(make_float2(a, b));  // low = a, high = b, RNE
    unsigned u; __builtin_memcpy(&u, &h, 4); return u;
}
static __device__ __forceinline__ short bf1(float a) {
    __hip_bfloat16 h = __float2bfloat16(a);                        // RNE
    unsigned short u; __builtin_memcpy(&u, &h, 2); return (short)u;
}

// ---- weight pre-swizzle: A-fragments of W^T (identical gather to B-frags of W) ----
__global__ void prep_w(const float* __restrict__ qkv_w,
                       const float* __restrict__ proj_w,
                       short* __restrict__ wb) {
    const int fid = blockIdx.x;     // 0..127 (96 qkv + 32 proj)
    const int l   = threadIdx.x;    // 0..63
    const int lq = l & 15, lg = l >> 4;
    bf16x8 v;
    if (fid < 96) {
        const int nt = fid >> 2, kk = fid & 3;
        #pragma unroll
        for (int j = 0; j < 8; ++j)
            v[j] = bf1(qkv_w[(kk*32 + lg*8 + j)*384 + nt*16 + lq]);
        *(bf16x8*)(wb + fid*512 + l*8) = v;
    } else {
        const int f2 = fid - 96;
        const int nt = f2 >> 2, kk = f2 & 3;
        #pragma unroll
        for (int j = 0; j < 8; ++j)
            v[j] = bf1(proj_w[(kk*32 + lg*8 + j)*128 + nt*16 + lq]);
        *(bf16x8*)(wb + PROJ_WOFF + f2*512 + l*8) = v;
    }
}

__global__ __launch_bounds__(256, 3)
void win_attn(const float* __restrict__ x,
              const float* __restrict__ mask,
              const float* __restrict__ qkv_b,
              const float* __restrict__ proj_b,
              const float* __restrict__ bias_table,
              const short* __restrict__ wb,
              float* __restrict__ out) {
    __shared__ __align__(16) short qa[64 * LDQ];    // q, then ao overlay (17408 B)
    __shared__ __align__(16) short kl[64 * LDQ];    // k                  (17408 B)
    __shared__ __align__(16) short vt[128 * LDV];   // v transposed       (18432 B)

    const int b    = blockIdx.x;
    const int tid  = threadIdx.x;
    const int l    = tid & 63;
    const int wave = tid >> 6;
    const int lq   = l & 15, lg = l >> 4;

    // ---- Phase 0: x^T B-frags, global -> regs (bf16). Row-clamp pads (OOB-safe). ----
    const float* xb = x + (size_t)b * (NTOK * CDIM);
    bf16x8 xf[4][4];
    #pragma unroll
    for (int mt = 0; mt < 4; ++mt) {
        int row = mt*16 + lq; if (row > 48) row = 48;
        const float* pr = xb + row*CDIM + lg*8;
        #pragma unroll
        for (int kk = 0; kk < 4; ++kk) {
            float4 f0 = *(const float4*)(pr + kk*32);
            float4 f1 = *(const float4*)(pr + kk*32 + 4);
            union { bf16x8 v; unsigned u[4]; } t;
            t.u[0] = pk2(f0.x, f0.y);
            t.u[1] = pk2(f0.z, f0.w);
            t.u[2] = pk2(f1.x, f1.y);
            t.u[3] = pk2(f1.z, f1.w);
            xf[mt][kk] = t.v;
        }
    }

    // ---- Phase 1: QKV^T = Wqkv^T(A) · x^T(B). Wave w owns wcol-tiles w*6..w*6+5. ----
    #pragma unroll
    for (int t = 0; t < 6; ++t) {
        const int nt = wave*6 + t;                   // 0..23: q 0-7, k 8-15, v 16-23
        bf16x8 wf[4];
        #pragma unroll
        for (int kk = 0; kk < 4; ++kk)
            wf[kk] = *(const bf16x8*)(wb + (nt*4 + kk)*512 + l*8);
        const f32x4 bia = *(const f32x4*)(qkv_b + nt*16 + lg*4);   // D rows = wcols
        f32x4 acc[4];
        #pragma unroll
        for (int mt = 0; mt < 4; ++mt) acc[mt] = bia;
        #pragma unroll
        for (int kk = 0; kk < 4; ++kk)
            #pragma unroll
            for (int mt = 0; mt < 4; ++mt)
                acc[mt] = __builtin_amdgcn_mfma_f32_16x16x32_bf16(wf[kk], xf[mt][kk], acc[mt], 0, 0, 0);
        // D: lane holds (wcol = nt*16+lg*4+r, tok = mt*16+lq); r consecutive -> b64 stores
        if (nt < 8) {                                // q (scaled)
            #pragma unroll
            for (int mt = 0; mt < 4; ++mt) {
                unsigned w0 = pk2(acc[mt][0]*SCALE, acc[mt][1]*SCALE);
                unsigned w1 = pk2(acc[mt][2]*SCALE, acc[mt][3]*SCALE);
                *(unsigned long long*)(qa + (mt*16 + lq)*LDQ + nt*16 + lg*4) =
                    (unsigned long long)w0 | ((unsigned long long)w1 << 32);
            }
        } else if (nt < 16) {                        // k
            #pragma unroll
            for (int mt = 0; mt < 4; ++mt) {
                unsigned w0 = pk2(acc[mt][0], acc[mt][1]);
                unsigned w1 = pk2(acc[mt][2], acc[mt][3]);
                *(unsigned long long*)(kl + (mt*16 + lq)*LDQ + (nt - 8)*16 + lg*4) =
                    (unsigned long long)w0 | ((unsigned long long)w1 << 32);
            }
        } else {                                     // v -> transposed vt[dim][tok]
            #pragma unroll
            for (int mt = 0; mt < 4; ++mt)
                #pragma unroll
                for (int r = 0; r < 4; ++r)
                    vt[((nt - 16)*16 + lg*4 + r)*LDV + mt*16 + lq] = bf1(acc[mt][r]);
        }
    }
    __syncthreads();

    // ---- Phase 2: attention, barrier-free. Wave owns q-rows m0..m0+15. ----
    const int m0 = wave * 16;
    const int qtok = m0 + lq;                        // this lane's q-row for ALL its S values
    const float* mwin = mask + (size_t)(b & (NWIN - 1)) * (NTOK * NTOK);

    // hoisted (head-independent) bias indices + mask values; ktok = nt*16+lg*4+r
    int   ridx[4][4]; float mval[4][4];
    #pragma unroll
    for (int nt = 0; nt < 4; ++nt)
        #pragma unroll
        for (int r = 0; r < 4; ++r) {
            const int kt = nt*16 + lg*4 + r;
            if (qtok < NTOK && kt < NTOK) {
                ridx[nt][r] = ((qtok/7 - kt/7 + 6)*13 + (qtok%7 - kt%7 + 6)) * 4;
                mval[nt][r] = mwin[qtok*NTOK + kt];
            } else { ridx[nt][r] = -1; mval[nt][r] = 0.f; }
        }

    // q B-frags for all heads (hoisted so ao overlay is safe)
    bf16x8 qf[4];
    #pragma unroll
    for (int h = 0; h < 4; ++h)
        qf[h] = *(const bf16x8*)(qa + (m0 + lq)*LDQ + h*32 + lg*8);

    const int src0 = lq + 16*((2*lg + 0) & 3);       // P-repack source lanes
    const int src1 = lq + 16*((2*lg + 1) & 3);
    const bool hi  = (lg >> 1);

    #pragma unroll
    for (int h = 0; h < 4; ++h) {
        // S^T tiles: D[ktok][qtok] = K(A) · Q^T(B)
        f32x4 s[4];
        #pragma unroll
        for (int nt = 0; nt < 4; ++nt) {
            bf16x8 kf = *(const bf16x8*)(kl + (nt*16 + lq)*LDQ + h*32 + lg*8);
            f32x4 z = {0.f, 0.f, 0.f, 0.f};
            s[nt] = __builtin_amdgcn_mfma_f32_16x16x32_bf16(kf, qf[h], z, 0, 0, 0);
        }
        // + rel-pos bias + mask; pads -> -1e30
        #pragma unroll
        for (int nt = 0; nt < 4; ++nt)
            #pragma unroll
            for (int r = 0; r < 4; ++r) {
                if (ridx[nt][r] >= 0) s[nt][r] += bias_table[ridx[nt][r] + h] + mval[nt][r];
                else                  s[nt][r] = -1e30f;
            }
        // softmax: lane holds full row (16 ktoks) x 4 lg-groups
        float mx = s[0][0];
        #pragma unroll
        for (int nt = 0; nt < 4; ++nt)
            #pragma unroll
            for (int r = 0; r < 4; ++r) mx = fmaxf(mx, s[nt][r]);
        mx = fmaxf(mx, __shfl_xor(mx, 16, 64));
        mx = fmaxf(mx, __shfl_xor(mx, 32, 64));
        float sum = 0.f;
        #pragma unroll
        for (int nt = 0; nt < 4; ++nt)
            #pragma unroll
            for (int r = 0; r < 4; ++r) {
                const float e = __expf(s[nt][r] - mx);
                s[nt][r] = e; sum += e;
            }
        sum += __shfl_xor(sum, 16, 64);
        sum += __shfl_xor(sum, 32, 64);
        const float inv = 1.0f / sum;
        // normalize + pack pairs (r0,r1 | r2,r3)
        unsigned pkv[4][2];
        #pragma unroll
        for (int nt = 0; nt < 4; ++nt) {
            pkv[nt][0] = pk2(s[nt][0]*inv, s[nt][1]*inv);
            pkv[nt][1] = pk2(s[nt][2]*inv, s[nt][3]*inv);
        }
        // repack to P^T B-frags: lane needs P[m0+lq][c*32+lg*8+j]
        bf16x8 pa[2];
        #pragma unroll
        for (int c = 0; c < 2; ++c) {
            union { bf16x8 v; unsigned u[4]; } t;
            unsigned a0, a1;
            a0 = __shfl((int)pkv[2*c][0], src0, 64); a1 = __shfl((int)pkv[2*c+1][0], src0, 64);
            t.u[0] = hi ? a1 : a0;
            a0 = __shfl((int)pkv[2*c][1], src0, 64); a1 = __shfl((int)pkv[2*c+1][1], src0, 64);
            t.u[1] = hi ? a1 : a0;
            a0 = __shfl((int)pkv[2*c][0], src1, 64); a1 = __shfl((int)pkv[2*c+1][0], src1, 64);
            t.u[2] = hi ? a1 : a0;
            a0 = __shfl((int)pkv[2*c][1], src1, 64); a1 = __shfl((int)pkv[2*c+1][1], src1, 64);
            t.u[3] = hi ? a1 : a0;
            pa[c] = t.v;
        }
        // PV (transposed): ao^T = V^T(A) · P^T(B); D rows = dims -> b64 ao stores
        #pragma unroll
        for (int dn = 0; dn < 2; ++dn) {
            f32x4 o = {0.f, 0.f, 0.f, 0.f};
            #pragma unroll
            for (int kk = 0; kk < 2; ++kk) {
                bf16x8 vf = *(const bf16x8*)(vt + (h*32 + dn*16 + lq)*LDV + kk*32 + lg*8);
                o = __builtin_amdgcn_mfma_f32_16x16x32_bf16(vf, pa[kk], o, 0, 0, 0);
            }
            unsigned w0 = pk2(o[0], o[1]);
            unsigned w1 = pk2(o[2], o[3]);
            *(unsigned long long*)(qa + (m0 + lq)*LDQ + h*32 + dn*16 + lg*4) =
                (unsigned long long)w0 | ((unsigned long long)w1 << 32);
        }
    }
    __syncthreads();   // all waves' ao complete

    // ---- Phase 3: out^T = Wp^T(A) · ao^T(B); coalesced dwordx4 stores ----
    bf16x8 ab[4][4];
    #pragma unroll
    for (int mt = 0; mt < 4; ++mt)
        #pragma unroll
        for (int kk = 0; kk < 4; ++kk)
            ab[mt][kk] = *(const bf16x8*)(qa + (mt*16 + lq)*LDQ + kk*32 + lg*8);

    float* ob = out + (size_t)b * (NTOK * CDIM);
    #pragma unroll
    for (int t = 0; t < 2; ++t) {
        const int nt = wave*2 + t;                   // ocol tile 0..7
        bf16x8 wf[4];
        #pragma unroll
        for (int kk = 0; kk < 4; ++kk)
            wf[kk] = *(const bf16x8*)(wb + PROJ_WOFF + (nt*4 + kk)*512 + l*8);
        const f32x4 pbv = *(const f32x4*)(proj_b + nt*16 + lg*4);
        f32x4 acc[4];
        #pragma unroll
        for (int mt = 0; mt < 4; ++mt) acc[mt] = pbv;
        #pragma unroll
        for (int kk = 0; kk < 4; ++kk)
            #pragma unroll
            for (int mt = 0; mt < 4; ++mt)
                acc[mt] = __builtin_amdgcn_mfma_f32_16x16x32_bf16(wf[kk], ab[mt][kk], acc[mt], 0, 0, 0);
        // D: (ocol = nt*16+lg*4+r, tok = mt*16+lq) -> out[tok][ocol], r consecutive
        #pragma unroll
        for (int mt = 0; mt < 4; ++mt) {
            const int tok = mt*16 + lq;
            if (tok < NTOK)
                *(f32x4*)(ob + tok*CDIM + nt*16 + lg*4) = acc[mt];
        }
    }
}

extern "C" void kernel_launch(void* const* d_in, const int* in_sizes, int n_in,
                              void* d_out, int out_size, void* d_ws, size_t ws_size,
                              hipStream_t stream) {
    (void)in_sizes; (void)n_in; (void)out_size; (void)ws_size;
    const float* x          = (const float*)d_in[0];
    const float* mask       = (const float*)d_in[1];
    const float* qkv_w      = (const float*)d_in[2];
    const float* qkv_b      = (const float*)d_in[3];
    const float* proj_w     = (const float*)d_in[4];
    const float* proj_b     = (const float*)d_in[5];
    const float* bias_table = (const float*)d_in[6];
    float* out = (float*)d_out;
    short* wb  = (short*)d_ws;   // 131072 B used

    hipLaunchKernelGGL(prep_w,   dim3(128),  dim3(64),  0, stream, qkv_w, proj_w, wb);
    hipLaunchKernelGGL(win_attn, dim3(4096), dim3(256), 0, stream,
                       x, mask, qkv_b, proj_b, bias_table, wb, out);
}

// Round 6
// 138.453 us; speedup vs baseline: 13.1276x; 1.1183x over previous
//
#include <hip/hip_runtime.h>
#include <hip/hip_bf16.h>

// Swin window attention, fully fused, bf16-MFMA, register-resident q/ao version.
// LDS holds ONLY k and v (35840 B -> 4 blocks/CU, 16 waves/CU). q and ao live in
// registers as packed D-fragments and are converted to MFMA A/B-fragments with the
// shfl-repack pattern validated by round 5's P-repack. One barrier total.
//   phase1a: k,v (transposed GEMM, col-split across waves) -> LDS
//   phase1b: q^T-stripe = Wq^T(A) . x^T(B) per wave -> qpk registers
//   phase1c: bias+mask hoist -> bmpk (bf16-packed, pads = -1e30)
//   phase2 : per head: qf=repack(qpk); S^T=K(A).Q^T(B); +bm; in-lane softmax;
//            pa=repack(pkv); ao^T=V^T(A).P^T(B) -> aopk registers   (no barriers)
//   phase3 : out_stripe = ao(A,repack(aopk)) . Wp(B); scalar dword stores
// MFMA 16x16x32 bf16 layouts (validated end-to-end rounds 3/5):
//   src0 A: lane holds A[lane&15][(lane>>4)*8+j]
//   src1 B: lane holds B[(lane>>4)*8+j][lane&15]
//   D:      lane holds D[(lane>>4)*4+r][lane&15]

typedef __attribute__((ext_vector_type(8))) short bf16x8;
typedef __attribute__((ext_vector_type(4))) float f32x4;

#define NTOK  49
#define CDIM  128
#define NWIN  256
#define LDQ   136     // shorts; 272 B row stride (odd 16B multiplier)
#define LDV   72      // shorts; 144 B row stride
#define SCALE 0.17677669529663687f
#define PROJ_WOFF 49152   // shorts: 96 frags * 512

static __device__ __forceinline__ unsigned pk2(float a, float b) {
    __hip_bfloat162 h = __float22bfloat162_rn(make_float2(a, b));  // low = a, high = b, RNE
    unsigned u; __builtin_memcpy(&u, &h, 4); return u;
}
static __device__ __forceinline__ short bf1(float a) {
    __hip_bfloat16 h = __float2bfloat16(a);                        // RNE
    unsigned short u; __builtin_memcpy(&u, &h, 2); return (short)u;
}
// D-packed pairs (consecutive cols of one row, row=lq-indexed) -> bf16x8 frag.
// Validated pattern (round 5 P-repack): elem j of result = ROW[m0+lq][base + lg*8 + j]
// given p0/p1 = packed words of col-tiles base/16 and base/16+1.
static __device__ __forceinline__ bf16x8 repack(unsigned p00, unsigned p01,
                                                unsigned p10, unsigned p11,
                                                int src0, int src1, bool hi) {
    union { bf16x8 v; unsigned u[4]; } t;
    unsigned a0, a1;
    a0 = __shfl((int)p00, src0, 64); a1 = __shfl((int)p10, src0, 64); t.u[0] = hi ? a1 : a0;
    a0 = __shfl((int)p01, src0, 64); a1 = __shfl((int)p11, src0, 64); t.u[1] = hi ? a1 : a0;
    a0 = __shfl((int)p00, src1, 64); a1 = __shfl((int)p10, src1, 64); t.u[2] = hi ? a1 : a0;
    a0 = __shfl((int)p01, src1, 64); a1 = __shfl((int)p11, src1, 64); t.u[3] = hi ? a1 : a0;
    return t.v;
}

// ---- weight pre-swizzle: per-tile fragments usable as A-frag of W^T or B-frag of W ----
__global__ void prep_w(const float* __restrict__ qkv_w,
                       const float* __restrict__ proj_w,
                       short* __restrict__ wb) {
    const int fid = blockIdx.x;     // 0..127 (96 qkv + 32 proj)
    const int l   = threadIdx.x;    // 0..63
    const int lq = l & 15, lg = l >> 4;
    bf16x8 v;
    if (fid < 96) {
        const int nt = fid >> 2, kk = fid & 3;
        #pragma unroll
        for (int j = 0; j < 8; ++j)
            v[j] = bf1(qkv_w[(kk*32 + lg*8 + j)*384 + nt*16 + lq]);
        *(bf16x8*)(wb + fid*512 + l*8) = v;
    } else {
        const int f2 = fid - 96;
        const int nt = f2 >> 2, kk = f2 & 3;
        #pragma unroll
        for (int j = 0; j < 8; ++j)
            v[j] = bf1(proj_w[(kk*32 + lg*8 + j)*128 + nt*16 + lq]);
        *(bf16x8*)(wb + PROJ_WOFF + f2*512 + l*8) = v;
    }
}

__global__ __launch_bounds__(256, 4)
void win_attn(const float* __restrict__ x,
              const float* __restrict__ mask,
              const float* __restrict__ qkv_b,
              const float* __restrict__ proj_b,
              const float* __restrict__ bias_table,
              const short* __restrict__ wb,
              float* __restrict__ out) {
    __shared__ __align__(16) short kl[64 * LDQ];    // k            (17408 B)
    __shared__ __align__(16) short vt[128 * LDV];   // v transposed (18432 B)

    const int b    = blockIdx.x;
    const int tid  = threadIdx.x;
    const int l    = tid & 63;
    const int wave = tid >> 6;
    const int lq   = l & 15, lg = l >> 4;
    const int m0   = wave * 16;

    // ---- Phase 0: x^T B-frags, global -> regs (bf16). Row-clamp pads (OOB-safe). ----
    const float* xb = x + (size_t)b * (NTOK * CDIM);
    bf16x8 xf[4][4];
    #pragma unroll
    for (int mt = 0; mt < 4; ++mt) {
        int row = mt*16 + lq; if (row > 48) row = 48;
        const float* pr = xb + row*CDIM + lg*8;
        #pragma unroll
        for (int kk = 0; kk < 4; ++kk) {
            float4 f0 = *(const float4*)(pr + kk*32);
            float4 f1 = *(const float4*)(pr + kk*32 + 4);
            union { bf16x8 v; unsigned u[4]; } t;
            t.u[0] = pk2(f0.x, f0.y);
            t.u[1] = pk2(f0.z, f0.w);
            t.u[2] = pk2(f1.x, f1.y);
            t.u[3] = pk2(f1.z, f1.w);
            xf[mt][kk] = t.v;
        }
    }

    // ---- Phase 1a: k,v via transposed GEMM (col-split: wave w owns tiles 8+4w..8+4w+3) ----
    #pragma unroll
    for (int t = 0; t < 4; ++t) {
        const int nt = 8 + wave*4 + t;               // 8..15 = k, 16..23 = v
        bf16x8 wf[4];
        #pragma unroll
        for (int kk = 0; kk < 4; ++kk)
            wf[kk] = *(const bf16x8*)(wb + (nt*4 + kk)*512 + l*8);
        const f32x4 bia = *(const f32x4*)(qkv_b + nt*16 + lg*4);   // D rows = wcols
        f32x4 acc[4];
        #pragma unroll
        for (int mt = 0; mt < 4; ++mt) acc[mt] = bia;
        #pragma unroll
        for (int kk = 0; kk < 4; ++kk)
            #pragma unroll
            for (int mt = 0; mt < 4; ++mt)
                acc[mt] = __builtin_amdgcn_mfma_f32_16x16x32_bf16(wf[kk], xf[mt][kk], acc[mt], 0, 0, 0);
        if (nt < 16) {                               // k -> kl[tok][kcol], b64 stores
            #pragma unroll
            for (int mt = 0; mt < 4; ++mt) {
                unsigned w0 = pk2(acc[mt][0], acc[mt][1]);
                unsigned w1 = pk2(acc[mt][2], acc[mt][3]);
                *(unsigned long long*)(kl + (mt*16 + lq)*LDQ + (nt - 8)*16 + lg*4) =
                    (unsigned long long)w0 | ((unsigned long long)w1 << 32);
            }
        } else {                                     // v -> transposed vt[dim][tok]
            #pragma unroll
            for (int mt = 0; mt < 4; ++mt)
                #pragma unroll
                for (int r = 0; r < 4; ++r)
                    vt[((nt - 16)*16 + lg*4 + r)*LDV + mt*16 + lq] = bf1(acc[mt][r]);
        }
    }

    // ---- Phase 1b: q^T-stripe = Wq^T(A) . x^T(B=own toks) -> qpk registers ----
    bf16x8 xa[4];
    #pragma unroll
    for (int mt = 0; mt < 4; ++mt)
        if (wave == mt) {
            #pragma unroll
            for (int kk = 0; kk < 4; ++kk) xa[kk] = xf[mt][kk];
        }
    unsigned qpk[8][2];   // qpk[nt][w]: q[m0+lq][nt*16+lg*4+{2w,2w+1}], scaled
    #pragma unroll
    for (int nt = 0; nt < 8; ++nt) {
        bf16x8 wf[4];
        #pragma unroll
        for (int kk = 0; kk < 4; ++kk)
            wf[kk] = *(const bf16x8*)(wb + (nt*4 + kk)*512 + l*8);
        f32x4 acc = *(const f32x4*)(qkv_b + nt*16 + lg*4);         // D rows = qcols
        #pragma unroll
        for (int kk = 0; kk < 4; ++kk)
            acc = __builtin_amdgcn_mfma_f32_16x16x32_bf16(wf[kk], xa[kk], acc, 0, 0, 0);
        qpk[nt][0] = pk2(acc[0]*SCALE, acc[1]*SCALE);
        qpk[nt][1] = pk2(acc[2]*SCALE, acc[3]*SCALE);
    }

    // ---- Phase 1c: bias+mask hoist -> bmpk (4 heads bf16-packed; pads = -1e30) ----
    const int qtok = m0 + lq;
    const float* mwin = mask + (size_t)(b & (NWIN - 1)) * (NTOK * NTOK);
    unsigned bmpk[4][4][2];
    {
        const unsigned NEG = pk2(-1e30f, -1e30f);
        #pragma unroll
        for (int nt = 0; nt < 4; ++nt)
            #pragma unroll
            for (int r = 0; r < 4; ++r) {
                const int kt = nt*16 + lg*4 + r;
                if (qtok < NTOK && kt < NTOK) {
                    const int ridx = (qtok/7 - kt/7 + 6)*13 + (qtok%7 - kt%7 + 6);
                    const f32x4 b4 = *(const f32x4*)(bias_table + ridx*4);
                    const float mv = mwin[qtok*NTOK + kt];
                    bmpk[nt][r][0] = pk2(b4[0] + mv, b4[1] + mv);
                    bmpk[nt][r][1] = pk2(b4[2] + mv, b4[3] + mv);
                } else {
                    bmpk[nt][r][0] = NEG; bmpk[nt][r][1] = NEG;
                }
            }
    }
    __syncthreads();   // kl/vt complete (the ONLY barrier)

    // ---- Phase 2: attention, barrier-free, q/ao in registers ----
    const int src0 = lq + 16*((2*lg + 0) & 3);       // repack source lanes
    const int src1 = lq + 16*((2*lg + 1) & 3);
    const bool hi  = (lg >> 1);
    unsigned aopk[8][2];                             // ao[m0+lq][tile*16+lg*4+{..}], tile=2h+dn

    #pragma unroll
    for (int h = 0; h < 4; ++h) {
        // q B-frag for this head from qpk (validated repack pattern)
        const bf16x8 qf = repack(qpk[2*h][0], qpk[2*h][1], qpk[2*h+1][0], qpk[2*h+1][1],
                                 src0, src1, hi);
        // S^T tiles: D[ktok][qtok] = K(A) . Q^T(B)
        f32x4 s[4];
        #pragma unroll
        for (int nt = 0; nt < 4; ++nt) {
            bf16x8 kf = *(const bf16x8*)(kl + (nt*16 + lq)*LDQ + h*32 + lg*8);
            f32x4 z = {0.f, 0.f, 0.f, 0.f};
            s[nt] = __builtin_amdgcn_mfma_f32_16x16x32_bf16(kf, qf, z, 0, 0, 0);
        }
        // + (bias+mask) from bmpk: head h is short (h&1) of word (h>>1)
        #pragma unroll
        for (int nt = 0; nt < 4; ++nt)
            #pragma unroll
            for (int r = 0; r < 4; ++r) {
                const unsigned u = bmpk[nt][r][h >> 1];
                const float bm = __uint_as_float((h & 1) ? (u & 0xffff0000u) : (u << 16));
                s[nt][r] += bm;
            }
        // softmax over the row (16 in-lane values x 4 lg-groups); tree reductions
        float mx;
        {
            float m_[4];
            #pragma unroll
            for (int nt = 0; nt < 4; ++nt)
                m_[nt] = fmaxf(fmaxf(s[nt][0], s[nt][1]), fmaxf(s[nt][2], s[nt][3]));
            mx = fmaxf(fmaxf(m_[0], m_[1]), fmaxf(m_[2], m_[3]));
        }
        mx = fmaxf(mx, __shfl_xor(mx, 16, 64));
        mx = fmaxf(mx, __shfl_xor(mx, 32, 64));
        float sum;
        {
            float s_[4];
            #pragma unroll
            for (int nt = 0; nt < 4; ++nt) {
                #pragma unroll
                for (int r = 0; r < 4; ++r)
                    s[nt][r] = __expf(s[nt][r] - mx);
                s_[nt] = (s[nt][0] + s[nt][1]) + (s[nt][2] + s[nt][3]);
            }
            sum = (s_[0] + s_[1]) + (s_[2] + s_[3]);
        }
        sum += __shfl_xor(sum, 16, 64);
        sum += __shfl_xor(sum, 32, 64);
        const float inv = 1.0f / sum;
        // normalize + pack pairs, then repack to P^T B-frags
        unsigned pkv[4][2];
        #pragma unroll
        for (int nt = 0; nt < 4; ++nt) {
            pkv[nt][0] = pk2(s[nt][0]*inv, s[nt][1]*inv);
            pkv[nt][1] = pk2(s[nt][2]*inv, s[nt][3]*inv);
        }
        bf16x8 pa[2];
        #pragma unroll
        for (int c = 0; c < 2; ++c)
            pa[c] = repack(pkv[2*c][0], pkv[2*c][1], pkv[2*c+1][0], pkv[2*c+1][1],
                           src0, src1, hi);
        // PV (transposed): ao^T = V^T(A) . P^T(B) -> aopk registers
        #pragma unroll
        for (int dn = 0; dn < 2; ++dn) {
            f32x4 o = {0.f, 0.f, 0.f, 0.f};
            #pragma unroll
            for (int kk = 0; kk < 2; ++kk) {
                bf16x8 vf = *(const bf16x8*)(vt + (h*32 + dn*16 + lq)*LDV + kk*32 + lg*8);
                o = __builtin_amdgcn_mfma_f32_16x16x32_bf16(vf, pa[kk], o, 0, 0, 0);
            }
            aopk[2*h + dn][0] = pk2(o[0], o[1]);
            aopk[2*h + dn][1] = pk2(o[2], o[3]);
        }
    }

    // ---- Phase 3: out_stripe = ao(A) . Wp(B); D rows = toks -> guarded dword stores ----
    bf16x8 ab[4];
    #pragma unroll
    for (int kk = 0; kk < 4; ++kk)
        ab[kk] = repack(aopk[2*kk][0], aopk[2*kk][1], aopk[2*kk+1][0], aopk[2*kk+1][1],
                        src0, src1, hi);
    float* ob = out + (size_t)b * (NTOK * CDIM);
    #pragma unroll
    for (int nt = 0; nt < 8; ++nt) {
        bf16x8 wf[4];
        #pragma unroll
        for (int kk = 0; kk < 4; ++kk)
            wf[kk] = *(const bf16x8*)(wb + PROJ_WOFF + (nt*4 + kk)*512 + l*8);
        const float pb = proj_b[nt*16 + lq];
        f32x4 acc = {pb, pb, pb, pb};
        #pragma unroll
        for (int kk = 0; kk < 4; ++kk)
            acc = __builtin_amdgcn_mfma_f32_16x16x32_bf16(ab[kk], wf[kk], acc, 0, 0, 0);
        #pragma unroll
        for (int r = 0; r < 4; ++r) {
            const int row = m0 + lg*4 + r;
            if (row < NTOK)
                ob[row*CDIM + nt*16 + lq] = acc[r];
        }
    }
}

extern "C" void kernel_launch(void* const* d_in, const int* in_sizes, int n_in,
                              void* d_out, int out_size, void* d_ws, size_t ws_size,
                              hipStream_t stream) {
    (void)in_sizes; (void)n_in; (void)out_size; (void)ws_size;
    const float* x          = (const float*)d_in[0];
    const float* mask       = (const float*)d_in[1];
    const float* qkv_w      = (const float*)d_in[2];
    const float* qkv_b      = (const float*)d_in[3];
    const float* proj_w     = (const float*)d_in[4];
    const float* proj_b     = (const float*)d_in[5];
    const float* bias_table = (const float*)d_in[6];
    float* out = (float*)d_out;
    short* wb  = (short*)d_ws;   // 131072 B used

    hipLaunchKernelGGL(prep_w,   dim3(128),  dim3(64),  0, stream, qkv_w, proj_w, wb);
    hipLaunchKernelGGL(win_attn, dim3(4096), dim3(256), 0, stream,
                       x, mask, qkv_b, proj_b, bias_table, wb, out);
}

// Round 8
// 132.825 us; speedup vs baseline: 13.6839x; 1.0424x over previous
//
#include <hip/hip_runtime.h>
#include <hip/hip_bf16.h>

// Swin window attention, fully fused, bf16-MFMA.
// (Resubmission of round 7 — previous bench died on an unresponsive container,
// kernel never ran.)
// Round-7 changes vs round 6:
//  - token-stripe QKV: each wave computes ALL 24 wcol-tiles for ITS OWN 16 tokens
//    (x loaded once per stripe, not 4x redundantly).
//  - unpadded 32 KB LDS (kl 64x128, vt 128x64) with 16B-unit XOR swizzle
//    (unit ^= row&7) -> 5 blocks/CU (160 KB exactly), launch_bounds(256,5).
//  - phase 3 transposed via A/B-frag duality (A-frag of ao == B-frag of ao^T):
//    out^T = Wp^T(A) . ao^T(B) -> r-consecutive ocols -> coalesced f32x4 stores.
// MFMA 16x16x32 bf16 layouts (validated end-to-end rounds 3/5/6):
//   src0 A: lane holds A[lane&15][(lane>>4)*8+j]
//   src1 B: lane holds B[(lane>>4)*8+j][lane&15]
//   D:      lane holds D[(lane>>4)*4+r][lane&15]

typedef __attribute__((ext_vector_type(8))) short bf16x8;
typedef __attribute__((ext_vector_type(4))) float f32x4;

#define NTOK  49
#define CDIM  128
#define NWIN  256
#define SCALE 0.17677669529663687f
#define PROJ_WOFF 49152   // shorts: 96 frags * 512

static __device__ __forceinline__ unsigned pk2(float a, float b) {
    __hip_bfloat162 h = __float22bfloat162_rn(make_float2(a, b));  // low = a, high = b, RNE
    unsigned u; __builtin_memcpy(&u, &h, 4); return u;
}
static __device__ __forceinline__ short bf1(float a) {
    __hip_bfloat16 h = __float2bfloat16(a);                        // RNE
    unsigned short u; __builtin_memcpy(&u, &h, 2); return (short)u;
}
// D-packed pairs (consecutive cols of one row, row=lq-indexed) -> bf16x8 frag.
// elem j of result = ROW[m0+lq][base + lg*8 + j]  (validated round 5/6)
static __device__ __forceinline__ bf16x8 repack(unsigned p00, unsigned p01,
                                                unsigned p10, unsigned p11,
                                                int src0, int src1, bool hi) {
    union { bf16x8 v; unsigned u[4]; } t;
    unsigned a0, a1;
    a0 = __shfl((int)p00, src0, 64); a1 = __shfl((int)p10, src0, 64); t.u[0] = hi ? a1 : a0;
    a0 = __shfl((int)p01, src0, 64); a1 = __shfl((int)p11, src0, 64); t.u[1] = hi ? a1 : a0;
    a0 = __shfl((int)p00, src1, 64); a1 = __shfl((int)p10, src1, 64); t.u[2] = hi ? a1 : a0;
    a0 = __shfl((int)p01, src1, 64); a1 = __shfl((int)p11, src1, 64); t.u[3] = hi ? a1 : a0;
    return t.v;
}

// ---- weight pre-swizzle: per-tile fragments = A-frags of W^T (== B-frags of W) ----
__global__ void prep_w(const float* __restrict__ qkv_w,
                       const float* __restrict__ proj_w,
                       short* __restrict__ wb) {
    const int fid = blockIdx.x;     // 0..127 (96 qkv + 32 proj)
    const int l   = threadIdx.x;    // 0..63
    const int lq = l & 15, lg = l >> 4;
    bf16x8 v;
    if (fid < 96) {
        const int nt = fid >> 2, kk = fid & 3;
        #pragma unroll
        for (int j = 0; j < 8; ++j)
            v[j] = bf1(qkv_w[(kk*32 + lg*8 + j)*384 + nt*16 + lq]);
        *(bf16x8*)(wb + fid*512 + l*8) = v;
    } else {
        const int f2 = fid - 96;
        const int nt = f2 >> 2, kk = f2 & 3;
        #pragma unroll
        for (int j = 0; j < 8; ++j)
            v[j] = bf1(proj_w[(kk*32 + lg*8 + j)*128 + nt*16 + lq]);
        *(bf16x8*)(wb + PROJ_WOFF + f2*512 + l*8) = v;
    }
}

__global__ __launch_bounds__(256, 5)
void win_attn(const float* __restrict__ x,
              const float* __restrict__ mask,
              const float* __restrict__ qkv_b,
              const float* __restrict__ proj_b,
              const float* __restrict__ bias_table,
              const short* __restrict__ wb,
              float* __restrict__ out) {
    // unpadded, XOR-swizzled in 16B units: phys = row*stride + ((u ^ (row&7))<<3) + (col&7)
    __shared__ __align__(16) short kl[64 * 128];    // k            (16384 B)
    __shared__ __align__(16) short vt[128 * 64];    // v transposed (16384 B)

    const int b    = blockIdx.x;
    const int tid  = threadIdx.x;
    const int l    = tid & 63;
    const int wave = tid >> 6;
    const int lq   = l & 15, lg = l >> 4;
    const int m0   = wave * 16;
    const int qtok = m0 + lq;

    // ---- Phase 0: own-stripe x^T B-frags, global -> regs (bf16). Row-clamp pads. ----
    const float* xb = x + (size_t)b * (NTOK * CDIM);
    bf16x8 xa[4];
    {
        int row = qtok; if (row > 48) row = 48;
        const float* pr = xb + row*CDIM + lg*8;
        #pragma unroll
        for (int kk = 0; kk < 4; ++kk) {
            float4 f0 = *(const float4*)(pr + kk*32);
            float4 f1 = *(const float4*)(pr + kk*32 + 4);
            union { bf16x8 v; unsigned u[4]; } t;
            t.u[0] = pk2(f0.x, f0.y);
            t.u[1] = pk2(f0.z, f0.w);
            t.u[2] = pk2(f1.x, f1.y);
            t.u[3] = pk2(f1.z, f1.w);
            xa[kk] = t.v;
        }
    }

    // ---- Phase 1: all 24 wcol-tiles for own token stripe. q->regs, k/v->LDS. ----
    unsigned qpk[8][2];   // qpk[nt][w]: q[qtok][nt*16+lg*4+{2w,2w+1}], scaled
    #pragma unroll
    for (int nt = 0; nt < 24; ++nt) {
        bf16x8 wf[4];
        #pragma unroll
        for (int kk = 0; kk < 4; ++kk)
            wf[kk] = *(const bf16x8*)(wb + (nt*4 + kk)*512 + l*8);
        f32x4 acc = *(const f32x4*)(qkv_b + nt*16 + lg*4);         // D rows = wcols
        #pragma unroll
        for (int kk = 0; kk < 4; ++kk)
            acc = __builtin_amdgcn_mfma_f32_16x16x32_bf16(wf[kk], xa[kk], acc, 0, 0, 0);
        // D: lane holds (wcol = nt*16+lg*4+r, tok = qtok)
        if (nt < 8) {                                // q (scaled) -> registers
            qpk[nt][0] = pk2(acc[0]*SCALE, acc[1]*SCALE);
            qpk[nt][1] = pk2(acc[2]*SCALE, acc[3]*SCALE);
        } else if (nt < 16) {                        // k -> kl[tok][kcol], swizzled b64
            unsigned w0 = pk2(acc[0], acc[1]);
            unsigned w1 = pk2(acc[2], acc[3]);
            const int ub  = (nt - 8)*2 + (lg >> 1);
            const int off = qtok*128 + ((ub ^ (qtok & 7)) << 3) + (lg & 1)*4;
            *(unsigned long long*)(kl + off) =
                (unsigned long long)w0 | ((unsigned long long)w1 << 32);
        } else {                                     // v -> vt[dim][tok], swizzled b16
            #pragma unroll
            for (int r = 0; r < 4; ++r) {
                const int dim = (nt - 16)*16 + lg*4 + r;
                vt[dim*64 + (((qtok >> 3) ^ (dim & 7)) << 3) + (qtok & 7)] = bf1(acc[r]);
            }
        }
    }

    // ---- Phase 1c: bias+mask hoist -> bmpk (4 heads bf16-packed; pads = -1e30) ----
    const float* mwin = mask + (size_t)(b & (NWIN - 1)) * (NTOK * NTOK);
    unsigned bmpk[4][4][2];
    {
        const unsigned NEG = pk2(-1e30f, -1e30f);
        #pragma unroll
        for (int nt = 0; nt < 4; ++nt)
            #pragma unroll
            for (int r = 0; r < 4; ++r) {
                const int kt = nt*16 + lg*4 + r;
                if (qtok < NTOK && kt < NTOK) {
                    const int ridx = (qtok/7 - kt/7 + 6)*13 + (qtok%7 - kt%7 + 6);
                    const f32x4 b4 = *(const f32x4*)(bias_table + ridx*4);
                    const float mv = mwin[qtok*NTOK + kt];
                    bmpk[nt][r][0] = pk2(b4[0] + mv, b4[1] + mv);
                    bmpk[nt][r][1] = pk2(b4[2] + mv, b4[3] + mv);
                } else {
                    bmpk[nt][r][0] = NEG; bmpk[nt][r][1] = NEG;
                }
            }
    }
    __syncthreads();   // kl/vt complete (the ONLY barrier)

    // ---- Phase 2: attention, barrier-free, q/ao in registers ----
    const int src0 = lq + 16*((2*lg + 0) & 3);       // repack source lanes
    const int src1 = lq + 16*((2*lg + 1) & 3);
    const bool hi  = (lg >> 1);
    unsigned aopk[8][2];                             // ao[qtok][tile*16+lg*4+{..}], tile=2h+dn

    #pragma unroll
    for (int h = 0; h < 4; ++h) {
        // q B-frag for this head from qpk
        const bf16x8 qf = repack(qpk[2*h][0], qpk[2*h][1], qpk[2*h+1][0], qpk[2*h+1][1],
                                 src0, src1, hi);
        // S^T tiles: D[ktok][qtok] = K(A) . Q^T(B); kf from swizzled kl
        f32x4 s[4];
        #pragma unroll
        for (int nt = 0; nt < 4; ++nt) {
            const int krow = nt*16 + lq;
            const int u    = h*4 + lg;
            bf16x8 kf = *(const bf16x8*)(kl + krow*128 + ((u ^ (krow & 7)) << 3));
            f32x4 z = {0.f, 0.f, 0.f, 0.f};
            s[nt] = __builtin_amdgcn_mfma_f32_16x16x32_bf16(kf, qf, z, 0, 0, 0);
        }
        // + (bias+mask) from bmpk: head h is short (h&1) of word (h>>1)
        #pragma unroll
        for (int nt = 0; nt < 4; ++nt)
            #pragma unroll
            for (int r = 0; r < 4; ++r) {
                const unsigned u = bmpk[nt][r][h >> 1];
                const float bm = __uint_as_float((h & 1) ? (u & 0xffff0000u) : (u << 16));
                s[nt][r] += bm;
            }
        // softmax over the row (16 in-lane values x 4 lg-groups); tree reductions
        float mx;
        {
            float m_[4];
            #pragma unroll
            for (int nt = 0; nt < 4; ++nt)
                m_[nt] = fmaxf(fmaxf(s[nt][0], s[nt][1]), fmaxf(s[nt][2], s[nt][3]));
            mx = fmaxf(fmaxf(m_[0], m_[1]), fmaxf(m_[2], m_[3]));
        }
        mx = fmaxf(mx, __shfl_xor(mx, 16, 64));
        mx = fmaxf(mx, __shfl_xor(mx, 32, 64));
        float sum;
        {
            float s_[4];
            #pragma unroll
            for (int nt = 0; nt < 4; ++nt) {
                #pragma unroll
                for (int r = 0; r < 4; ++r)
                    s[nt][r] = __expf(s[nt][r] - mx);
                s_[nt] = (s[nt][0] + s[nt][1]) + (s[nt][2] + s[nt][3]);
            }
            sum = (s_[0] + s_[1]) + (s_[2] + s_[3]);
        }
        sum += __shfl_xor(sum, 16, 64);
        sum += __shfl_xor(sum, 32, 64);
        const float inv = 1.0f / sum;
        // normalize + pack pairs, then repack to P^T B-frags
        unsigned pkv[4][2];
        #pragma unroll
        for (int nt = 0; nt < 4; ++nt) {
            pkv[nt][0] = pk2(s[nt][0]*inv, s[nt][1]*inv);
            pkv[nt][1] = pk2(s[nt][2]*inv, s[nt][3]*inv);
        }
        bf16x8 pa[2];
        #pragma unroll
        for (int c = 0; c < 2; ++c)
            pa[c] = repack(pkv[2*c][0], pkv[2*c][1], pkv[2*c+1][0], pkv[2*c+1][1],
                           src0, src1, hi);
        // PV (transposed): ao^T = V^T(A) . P^T(B); vf from swizzled vt
        #pragma unroll
        for (int dn = 0; dn < 2; ++dn) {
            f32x4 o = {0.f, 0.f, 0.f, 0.f};
            #pragma unroll
            for (int kk = 0; kk < 2; ++kk) {
                const int dim = h*32 + dn*16 + lq;
                const int u   = kk*4 + lg;
                bf16x8 vf = *(const bf16x8*)(vt + dim*64 + ((u ^ (dim & 7)) << 3));
                o = __builtin_amdgcn_mfma_f32_16x16x32_bf16(vf, pa[kk], o, 0, 0, 0);
            }
            aopk[2*h + dn][0] = pk2(o[0], o[1]);
            aopk[2*h + dn][1] = pk2(o[2], o[3]);
        }
    }

    // ---- Phase 3: out^T = Wp^T(A) . ao^T(B); B-frag == A-frag of ao (duality) ----
    bf16x8 ab[4];
    #pragma unroll
    for (int kk = 0; kk < 4; ++kk)
        ab[kk] = repack(aopk[2*kk][0], aopk[2*kk][1], aopk[2*kk+1][0], aopk[2*kk+1][1],
                        src0, src1, hi);
    float* ob = out + (size_t)b * (NTOK * CDIM);
    #pragma unroll
    for (int nt = 0; nt < 8; ++nt) {
        bf16x8 wf[4];
        #pragma unroll
        for (int kk = 0; kk < 4; ++kk)
            wf[kk] = *(const bf16x8*)(wb + PROJ_WOFF + (nt*4 + kk)*512 + l*8);
        f32x4 acc = *(const f32x4*)(proj_b + nt*16 + lg*4);        // D rows = ocols
        #pragma unroll
        for (int kk = 0; kk < 4; ++kk)
            acc = __builtin_amdgcn_mfma_f32_16x16x32_bf16(wf[kk], ab[kk], acc, 0, 0, 0);
        // D: (ocol = nt*16+lg*4+r, tok = qtok) -> out[tok][ocol], r consecutive -> f32x4
        if (qtok < NTOK)
            *(f32x4*)(ob + qtok*CDIM + nt*16 + lg*4) = acc;
    }
}

extern "C" void kernel_launch(void* const* d_in, const int* in_sizes, int n_in,
                              void* d_out, int out_size, void* d_ws, size_t ws_size,
                              hipStream_t stream) {
    (void)in_sizes; (void)n_in; (void)out_size; (void)ws_size;
    const float* x          = (const float*)d_in[0];
    const float* mask       = (const float*)d_in[1];
    const float* qkv_w      = (const float*)d_in[2];
    const float* qkv_b      = (const float*)d_in[3];
    const float* proj_w     = (const float*)d_in[4];
    const float* proj_b     = (const float*)d_in[5];
    const float* bias_table = (const float*)d_in[6];
    float* out = (float*)d_out;
    short* wb  = (short*)d_ws;   // 131072 B used

    hipLaunchKernelGGL(prep_w,   dim3(128),  dim3(64),  0, stream, qkv_w, proj_w, wb);
    hipLaunchKernelGGL(win_attn, dim3(4096), dim3(256), 0, stream,
                       x, mask, qkv_b, proj_b, bias_table, wb, out);
}